// Round 7
// baseline (621.766 us; speedup 1.0000x reference)
//
#include <hip/hip_runtime.h>
#include <hip/hip_bf16.h>

// Problem constants
#define DM    1024          // d_model
#define NH    2             // heads
#define IDX   32            // idx dim per head
#define HQ    (NH*IDX)      // 64 query cols
#define TT    4096          // tokens per batch
#define BB    2             // batch
#define RR    (BB*TT)       // 8192 total rows
#define NC    112           // padded projection cols (64 Q + 32 K + 2 w + 14 pad)
#define NTIL  7             // NC/16
#define SCW   512           // score s-chunk width
#define SCH   (TT/SCW)      // 8 s-chunks per batch

// DIAGNOSTIC ROUND: opaque repetition factors so each kernel's dispatch
// exceeds the ~80us harness fills and surfaces in the top-5 counter table
// with per-kernel dur/WRITE_SIZE/occupancy. reps passed at runtime; all
// base pointers offset by (rep & zoff) with zoff==0 -> identical behavior,
// but compiler cannot prove loop-invariance (anti-DCE, rule #17).
#define REP_PREP  64
#define REP_PROJ  16
#define REP_SCORE 6

typedef short  s16x8 __attribute__((ext_vector_type(8)));
typedef float  f32x4 __attribute__((ext_vector_type(4)));

// HW bf16 convert (compiler emits v_cvt_pk_bf16_f32 / RNE).
__device__ __forceinline__ unsigned short f2bf(float f) {
    __hip_bfloat16 h = __float2bfloat16(f);
    return __builtin_bit_cast(unsigned short, h);
}

// ---------------------------------------------------------------------------
// Kernel 1: pack Wq|Wk|Ww into transposed bf16 WcatT[NC][DM]
// ---------------------------------------------------------------------------
__global__ __launch_bounds__(256) void prep_wcat(const float* __restrict__ Wq0,
                                                 const float* __restrict__ Wk0,
                                                 const float* __restrict__ Ww0,
                                                 unsigned short* __restrict__ WcatT0,
                                                 int reps, int zoff) {
    int idx = blockIdx.x * 256 + threadIdx.x;        // NC*DM total
    int j = idx >> 10;                               // col  (0..111)
    int i = idx & 1023;                              // k    (0..1023)
    for (int rep = 0; rep < reps; ++rep) {
        const float* Wq = Wq0 + (rep & zoff);
        const float* Wk = Wk0 + (rep & zoff);
        const float* Ww = Ww0 + (rep & zoff);
        unsigned short* WcatT = WcatT0 + (rep & zoff);
        float v = 0.f;
        if (j < 64)       v = Wq[i * HQ + j];
        else if (j < 96)  v = Wk[i * IDX + (j - 64)];
        else if (j < 98)  v = Ww[i * NH + (j - 96)];
        WcatT[j * DM + i] = f2bf(v);
    }
}

// ---------------------------------------------------------------------------
// Kernel 2: projections (R2 topology: 256 blocks, 4 waves = 2 stripes x
// 2 K-halves; x read/converted once). HW cvt + unroll 4.
// ---------------------------------------------------------------------------
__global__ __launch_bounds__(256) void proj_kernel(const float* __restrict__ x0,
                                                   const unsigned short* __restrict__ WcatT0,
                                                   unsigned short* __restrict__ Qb0,
                                                   unsigned short* __restrict__ Kb0,
                                                   float* __restrict__ wb0,
                                                   int reps, int zoff) {
    __shared__ float red[2][NTIL][64][4];            // 14336 B

    const int wave  = threadIdx.x >> 6;              // 0..3
    const int lane  = threadIdx.x & 63;
    const int sl    = wave >> 1;                     // stripe within block
    const int khalf = wave & 1;
    const int stripe = blockIdx.x * 2 + sl;          // 0..511
    const int r0    = stripe * 16;
    const int lrow  = lane & 15;
    const int lseg  = lane >> 4;

    for (int rep = 0; rep < reps; ++rep) {
        const float*          x     = x0 + (rep & zoff);
        const unsigned short* WcatT = WcatT0 + (rep & zoff);
        unsigned short*       Qb    = Qb0 + (rep & zoff);
        unsigned short*       Kb    = Kb0 + (rep & zoff);
        float*                wb    = wb0 + (rep & zoff);

        f32x4 acc[NTIL] = {};

        const float*          xr = x + (size_t)(r0 + lrow) * DM + khalf * 512 + lseg * 8;
        const unsigned short* wr = WcatT + (size_t)lrow * DM + khalf * 512 + lseg * 8;

        #pragma unroll 4
        for (int kc = 0; kc < 512; kc += 32) {
            float4 a0 = *(const float4*)(xr + kc);
            float4 a1 = *(const float4*)(xr + kc + 4);
            s16x8 af;
            af[0] = (short)f2bf(a0.x); af[1] = (short)f2bf(a0.y);
            af[2] = (short)f2bf(a0.z); af[3] = (short)f2bf(a0.w);
            af[4] = (short)f2bf(a1.x); af[5] = (short)f2bf(a1.y);
            af[6] = (short)f2bf(a1.z); af[7] = (short)f2bf(a1.w);
            #pragma unroll
            for (int t = 0; t < NTIL; ++t) {
                s16x8 bfv = *(const s16x8*)(wr + (size_t)t * 16 * DM + kc);
                acc[t] = __builtin_amdgcn_mfma_f32_16x16x32_bf16(af, bfv, acc[t], 0, 0, 0);
            }
        }

        if (khalf == 1) {
            #pragma unroll
            for (int t = 0; t < NTIL; ++t)
                *(f32x4*)&red[sl][t][lane][0] = acc[t];
        }
        __syncthreads();
        if (khalf == 0) {
            #pragma unroll
            for (int t = 0; t < NTIL; ++t) {
                acc[t] += *(const f32x4*)&red[sl][t][lane][0];
                const int col = t * 16 + lrow;
                #pragma unroll
                for (int r = 0; r < 4; ++r) {
                    int row = r0 + lseg * 4 + r;
                    float v = acc[t][r];
                    if (col < 64)       Qb[(size_t)row * HQ + col]         = f2bf(v);
                    else if (col < 96)  Kb[(size_t)row * IDX + (col - 64)] = f2bf(v);
                    else if (col < 98)  wb[(size_t)row * NH + (col - 96)]  = v;
                }
            }
        }
        __syncthreads();   // WAR: next rep's red[] writes vs this rep's reads
    }
}

// ---------------------------------------------------------------------------
// Kernel 3: scores with LDS-transpose store staging (R6 structure).
// ---------------------------------------------------------------------------
__global__ __launch_bounds__(256) void score_kernel(const unsigned short* __restrict__ Qb0,
                                                    const unsigned short* __restrict__ Kb0,
                                                    const float* __restrict__ wb0,
                                                    float* __restrict__ out0,
                                                    int reps, int zoff) {
    __shared__ float lds[4][2048];       // 8 KB per wave, 32 KB per block

    const int rb   = blockIdx.x >> 3;    // 0..127 row-block (64 rows)
    const int sc   = blockIdx.x & (SCH - 1);
    const int wave = threadIdx.x >> 6;
    const int lane = threadIdx.x & 63;
    const int trow = lane & 15;
    const int lseg = lane >> 4;

    const int t0 = rb * 64 + wave * 16;          // global row in [0,8192)
    const int b  = t0 >> 12;                     // batch

    const int q32   = lane & 31;                 // drain: quad index 0..31
    const int thalf = lane >> 5;                 // drain: row parity

    float* wlds = &lds[wave][0];
    const f32x4 zero = {0.f, 0.f, 0.f, 0.f};
    const int s0 = sc * SCW;

    for (int rep = 0; rep < reps; ++rep) {
        const unsigned short* Qb  = Qb0 + (rep & zoff);
        const unsigned short* Kb  = Kb0 + (rep & zoff);
        const float*          wb  = wb0 + (rep & zoff);
        float*                out = out0 + (rep & zoff);

        const unsigned short* qrow = Qb + (size_t)(t0 + trow) * HQ + lseg * 8;
        s16x8 qb0 = *(const s16x8*)(qrow);
        s16x8 qb1 = *(const s16x8*)(qrow + IDX);
        float2 wt = *(const float2*)(wb + (size_t)(t0 + trow) * NH);

        const unsigned short* kbase =
            Kb + ((size_t)(b * TT) + s0 + trow) * IDX + lseg * 8;

        for (int span = 0; span < 4; ++span) {
            const int sbase = s0 + span * 128;

            #pragma unroll
            for (int it = 0; it < 8; ++it) {
                s16x8 kb = *(const s16x8*)(kbase + (size_t)(span * 8 + it) * 16 * IDX);
                f32x4 d0 = __builtin_amdgcn_mfma_f32_16x16x32_bf16(kb, qb0, zero, 0, 0, 0);
                f32x4 d1 = __builtin_amdgcn_mfma_f32_16x16x32_bf16(kb, qb1, zero, 0, 0, 0);
                f32x4 v;
                #pragma unroll
                for (int r = 0; r < 4; ++r)
                    v[r] = wt.x * fmaxf(d0[r], 0.f) + wt.y * fmaxf(d1[r], 0.f);
                const int quad = it * 4 + lseg;
                *(f32x4*)&wlds[trow * 128 + ((quad ^ (trow & 7)) << 2)] = v;
            }

            asm volatile("s_waitcnt lgkmcnt(0)" ::: "memory");

            #pragma unroll
            for (int j = 0; j < 8; ++j) {
                const int t = 2 * j + thalf;
                f32x4 v = *(const f32x4*)&wlds[t * 128 + ((q32 ^ (t & 7)) << 2)];
                *(f32x4*)(out + (size_t)(t0 + t) * TT + sbase + q32 * 4) = v;
            }

            asm volatile("s_waitcnt lgkmcnt(0)" ::: "memory");
        }
    }
}

// ---------------------------------------------------------------------------
extern "C" void kernel_launch(void* const* d_in, const int* in_sizes, int n_in,
                              void* d_out, int out_size, void* d_ws, size_t ws_size,
                              hipStream_t stream) {
    const float* x  = (const float*)d_in[0];
    const float* Wq = (const float*)d_in[1];
    const float* Wk = (const float*)d_in[2];
    const float* Ww = (const float*)d_in[3];
    float* out = (float*)d_out;

    // workspace layout (16B aligned)
    char* ws = (char*)d_ws;
    unsigned short* WcatT = (unsigned short*)ws;                    // NC*DM*2   = 229376
    unsigned short* Qb    = (unsigned short*)(ws + 256 * 1024);     // RR*HQ*2   = 1 MB
    unsigned short* Kb    = (unsigned short*)(ws + 256 * 1024 + 1024 * 1024);  // RR*IDX*2 = 512 KB
    float*          wb    = (float*)(ws + 256 * 1024 + 1024 * 1024 + 512 * 1024); // RR*NH*4 = 64 KB

    hipLaunchKernelGGL(prep_wcat, dim3((NC * DM) / 256), dim3(256), 0, stream,
                       Wq, Wk, Ww, WcatT, REP_PREP, 0);
    hipLaunchKernelGGL(proj_kernel, dim3(RR / 32), dim3(256), 0, stream,
                       x, WcatT, Qb, Kb, wb, REP_PROJ, 0);
    hipLaunchKernelGGL(score_kernel, dim3((RR / 64) * SCH), dim3(256), 0, stream,
                       Qb, Kb, wb, out, REP_SCORE, 0);
}

// Round 8
// 52.567 us; speedup vs baseline: 11.8280x; 11.8280x over previous
//
#include <hip/hip_runtime.h>
#include <hip/hip_bf16.h>

// Problem constants
#define DM    1024          // d_model
#define NH    2             // heads
#define IDX   32            // idx dim per head
#define HQ    (NH*IDX)      // 64 query cols
#define TT    4096          // tokens per batch
#define BB    2             // batch
#define RR    (BB*TT)       // 8192 total rows
#define NC    112           // padded projection cols (64 Q + 32 K + 2 w + 14 pad)
#define NTIL  7             // NC/16
#define SCW   512           // score s-chunk width
#define SCH   (TT/SCW)      // 8 s-chunks per batch

typedef short  s16x8 __attribute__((ext_vector_type(8)));
typedef float  f32x4 __attribute__((ext_vector_type(4)));

// HW bf16 convert (compiler emits v_cvt_pk_bf16_f32 / RNE).
__device__ __forceinline__ unsigned short f2bf(float f) {
    __hip_bfloat16 h = __float2bfloat16(f);
    return __builtin_bit_cast(unsigned short, h);
}

// ---------------------------------------------------------------------------
// Kernel 1: pack Wq|Wk|Ww into transposed bf16 WcatT[NC][DM]
// ---------------------------------------------------------------------------
__global__ __launch_bounds__(256) void prep_wcat(const float* __restrict__ Wq,
                                                 const float* __restrict__ Wk,
                                                 const float* __restrict__ Ww,
                                                 unsigned short* __restrict__ WcatT) {
    int idx = blockIdx.x * 256 + threadIdx.x;        // NC*DM total
    int j = idx >> 10;                               // col  (0..111)
    int i = idx & 1023;                              // k    (0..1023)
    float v = 0.f;
    if (j < 64)       v = Wq[i * HQ + j];
    else if (j < 96)  v = Wk[i * IDX + (j - 64)];
    else if (j < 98)  v = Ww[i * NH + (j - 96)];
    WcatT[j * DM + i] = f2bf(v);
}

// ---------------------------------------------------------------------------
// Kernel 2: projections — latency-bound fix (R7 diag: 4 waves/CU, 5.8% BW).
// 512 blocks x 512 threads (8 waves). Block = one 16-row stripe; wave =
// one K-slice of 128 (4 fully-unrolled iters -> ~8KB/wave loads in flight).
// LDS 57KB -> 2 blocks/CU -> 16 waves/CU. 8-way LDS reduce, tile-per-wave
// epilogue.
// ---------------------------------------------------------------------------
__global__ __launch_bounds__(512) void proj_kernel(const float* __restrict__ x,
                                                   const unsigned short* __restrict__ WcatT,
                                                   unsigned short* __restrict__ Qb,
                                                   unsigned short* __restrict__ Kb,
                                                   float* __restrict__ wb) {
    __shared__ float red[8][NTIL][64][4];            // 57344 B

    const int wave = threadIdx.x >> 6;               // K-slice 0..7
    const int lane = threadIdx.x & 63;
    const int r0   = blockIdx.x * 16;
    const int lrow = lane & 15;
    const int lseg = lane >> 4;

    f32x4 acc[NTIL] = {};

    const float*          xr = x + (size_t)(r0 + lrow) * DM + wave * 128 + lseg * 8;
    const unsigned short* wr = WcatT + (size_t)lrow * DM + wave * 128 + lseg * 8;

    #pragma unroll
    for (int kc = 0; kc < 128; kc += 32) {
        float4 a0 = *(const float4*)(xr + kc);
        float4 a1 = *(const float4*)(xr + kc + 4);
        s16x8 af;
        af[0] = (short)f2bf(a0.x); af[1] = (short)f2bf(a0.y);
        af[2] = (short)f2bf(a0.z); af[3] = (short)f2bf(a0.w);
        af[4] = (short)f2bf(a1.x); af[5] = (short)f2bf(a1.y);
        af[6] = (short)f2bf(a1.z); af[7] = (short)f2bf(a1.w);
        #pragma unroll
        for (int t = 0; t < NTIL; ++t) {
            s16x8 bfv = *(const s16x8*)(wr + (size_t)t * 16 * DM + kc);
            acc[t] = __builtin_amdgcn_mfma_f32_16x16x32_bf16(af, bfv, acc[t], 0, 0, 0);
        }
    }

    #pragma unroll
    for (int t = 0; t < NTIL; ++t)
        *(f32x4*)&red[wave][t][lane][0] = acc[t];
    __syncthreads();

    if (wave < NTIL) {
        f32x4 s = {};
        #pragma unroll
        for (int sl = 0; sl < 8; ++sl)
            s += *(const f32x4*)&red[sl][wave][lane][0];
        const int col = wave * 16 + lrow;
        #pragma unroll
        for (int r = 0; r < 4; ++r) {
            int row = r0 + lseg * 4 + r;
            float v = s[r];
            if (col < 64)       Qb[(size_t)row * HQ + col]         = f2bf(v);
            else if (col < 96)  Kb[(size_t)row * IDX + (col - 64)] = f2bf(v);
            else if (col < 98)  wb[(size_t)row * NH + (col - 96)]  = v;
        }
    }
}

// ---------------------------------------------------------------------------
// Kernel 3: scores (R5 structure — measured at the 6.1 TB/s write ceiling).
// Swapped mfma operands: D = K_frag * Q_frag -> lane holds 4 consecutive
// s-values of one t-row -> dwordx4 stores. Wave: 16 t-rows x 512 s-cols.
// ---------------------------------------------------------------------------
__global__ __launch_bounds__(256) void score_kernel(const unsigned short* __restrict__ Qb,
                                                    const unsigned short* __restrict__ Kb,
                                                    const float* __restrict__ wb,
                                                    float* __restrict__ out) {
    const int rb   = blockIdx.x >> 3;    // 0..127 row-block (64 rows)
    const int sc   = blockIdx.x & (SCH - 1);
    const int wave = threadIdx.x >> 6;
    const int lane = threadIdx.x & 63;
    const int trow = lane & 15;
    const int lseg = lane >> 4;

    const int t0 = rb * 64 + wave * 16;          // global row in [0,8192)
    const int b  = t0 >> 12;                     // batch

    const unsigned short* qrow = Qb + (size_t)(t0 + trow) * HQ + lseg * 8;
    s16x8 qb0 = *(const s16x8*)(qrow);           // head 0 fragment (B operand)
    s16x8 qb1 = *(const s16x8*)(qrow + IDX);     // head 1

    float2 wt = *(const float2*)(wb + (size_t)(t0 + trow) * NH);

    const int s0 = sc * SCW;
    const unsigned short* kbase =
        Kb + ((size_t)(b * TT) + s0 + trow) * IDX + lseg * 8;
    float* obase = out + (size_t)(t0 + trow) * TT + s0 + lseg * 4;

    const f32x4 zero = {0.f, 0.f, 0.f, 0.f};

    #pragma unroll 4
    for (int it = 0; it < SCW / 16; ++it) {
        s16x8 kb = *(const s16x8*)(kbase + (size_t)it * 16 * IDX);
        f32x4 d0 = __builtin_amdgcn_mfma_f32_16x16x32_bf16(kb, qb0, zero, 0, 0, 0);
        f32x4 d1 = __builtin_amdgcn_mfma_f32_16x16x32_bf16(kb, qb1, zero, 0, 0, 0);
        f32x4 v;
        #pragma unroll
        for (int r = 0; r < 4; ++r)
            v[r] = wt.x * fmaxf(d0[r], 0.f) + wt.y * fmaxf(d1[r], 0.f);
        *(f32x4*)(obase + it * 16) = v;
    }
}

// ---------------------------------------------------------------------------
extern "C" void kernel_launch(void* const* d_in, const int* in_sizes, int n_in,
                              void* d_out, int out_size, void* d_ws, size_t ws_size,
                              hipStream_t stream) {
    const float* x  = (const float*)d_in[0];
    const float* Wq = (const float*)d_in[1];
    const float* Wk = (const float*)d_in[2];
    const float* Ww = (const float*)d_in[3];
    float* out = (float*)d_out;

    // workspace layout (16B aligned)
    char* ws = (char*)d_ws;
    unsigned short* WcatT = (unsigned short*)ws;                    // NC*DM*2   = 229376
    unsigned short* Qb    = (unsigned short*)(ws + 256 * 1024);     // RR*HQ*2   = 1 MB
    unsigned short* Kb    = (unsigned short*)(ws + 256 * 1024 + 1024 * 1024);  // RR*IDX*2 = 512 KB
    float*          wb    = (float*)(ws + 256 * 1024 + 1024 * 1024 + 512 * 1024); // RR*NH*4 = 64 KB

    hipLaunchKernelGGL(prep_wcat, dim3((NC * DM) / 256), dim3(256), 0, stream,
                       Wq, Wk, Ww, WcatT);
    hipLaunchKernelGGL(proj_kernel, dim3(RR / 16), dim3(512), 0, stream,
                       x, WcatT, Qb, Kb, wb);
    hipLaunchKernelGGL(score_kernel, dim3((RR / 64) * SCH), dim3(256), 0, stream,
                       Qb, Kb, wb, out);
}